// Round 6
// baseline (92.005 us; speedup 1.0000x reference)
//
#include <hip/hip_runtime.h>

// Fully-fused 4-level db4 DWT (pywt wavedec, symmetric, level=4).
// Input  trajectory: [B=16, T=4096, F=256] f32, feature-fastest.
// Output: [B, T, 5, F] f32; bands [cA4, cD4, cD3, cD2, cD1], zero-padded to T.
//
// R6: two kernels.
//  - dwt_interior: k in [2,63] (no reflection) via POLYPHASE ROLLING WINDOWS:
//    level-(l+1) row r is computed the moment level-l row 2r+7 exists, so
//    8-deep circular buffers suffice (taps [2r,2r+7] == last 8 produced rows,
//    exact). Arrays: xw[8]+Aw[8]+Bw[8]+Cw[8] -> ~60 VGPR -> high occupancy.
//    Also carries the zero-fill blocks (prefix zeros, dwordx4 nt stores).
//  - dwt_edge: k in {0,1,64,65} with full per-thread arrays and constant-folded
//    symmetric reflection (verbatim verified round-4 code). 64 blocks, its own
//    (high) VGPR budget doesn't throttle the interior kernel.
//
// out[n] = sum_j x_sym[2n+j-6] * DEC[7-j]; refl: i<0 -> -1-i, i>=L -> 2L-1-i.
// Lengths: L1=2051, L2=1029, L3=518, L4=262.

namespace {
constexpr int T_LEN = 4096;
constexpr int F_DIM = 256;
constexpr int NB    = 5;
constexpr int L1 = 2051, L2 = 1029, L3 = 518, L4 = 262;
}

typedef float f32x4 __attribute__((ext_vector_type(4)));

__device__ __constant__ float RLO[8] = {
     0.23037781330885523f,   0.7148465705525415f,   0.6308807679295904f,
    -0.02798376941698385f,  -0.18703481171888114f,  0.030841381835986965f,
     0.032883011666982945f, -0.010597401784997278f };

__device__ __constant__ float RHI[8] = {
    -0.010597401784997278f, -0.032883011666982945f, 0.030841381835986965f,
     0.18703481171888114f,  -0.02798376941698385f, -0.6308807679295904f,
     0.7148465705525415f,   -0.23037781330885523f };

__device__ __host__ constexpr int refl(int i, int L) {
    return (i < 0) ? (-1 - i) : ((i >= L) ? (2 * L - 1 - i) : i);
}

__device__ __forceinline__ void nt_store(float* p, float v) {
    __builtin_nontemporal_store(v, p);
}

// ---- zero-fill: rows [t0,t1) each get a Z*1KB zero prefix (dwordx4) ----
template<int Z>
__device__ __forceinline__ void fill_zeros(float* __restrict__ outB,
                                           int t0, int t1, int tid)
{
    const f32x4 z4 = {0.f, 0.f, 0.f, 0.f};
    for (int t = t0; t < t1; ++t) {
        float* row = outB + (size_t)t * NB * F_DIM;
        #pragma unroll
        for (int c0 = 0; c0 < Z * F_DIM; c0 += 4 * F_DIM) {
            const int c = c0 + tid * 4;
            if (c < Z * F_DIM)
                __builtin_nontemporal_store(z4, (f32x4*)(row + c));
        }
    }
}

// ---- interior cascade, k in [2,63]: rolling 8-deep windows, no reflection ----
__device__ __forceinline__ void cascade_interior(const float* __restrict__ inb,
                                                 float* __restrict__ outb, int k)
{
    const int t1b = 32 * k - 42;
    const int t2b = 16 * k - 18;
    const int t3b = 8  * k - 6;

    float xw[8], Aw[8], Bw[8], Cw[8];

    // prime input window: locals 0..7 = rows 2*t1b-6 .. 2*t1b+1 (in-bounds for k>=2)
    #pragma unroll
    for (int j = 0; j < 8; ++j)
        xw[j] = inb[(size_t)(2 * t1b - 6 + j) * F_DIM];

    #pragma unroll
    for (int r1 = 0; r1 < 74; ++r1) {
        // level 1: taps = input locals [2r1, 2r1+7] (circular mod-8, static)
        float a1 = 0.f, d1 = 0.f;
        #pragma unroll
        for (int j = 0; j < 8; ++j) {
            const float v = xw[(2 * r1 + j) & 7];
            a1 = fmaf(v, RLO[j], a1);
            d1 = fmaf(v, RHI[j], d1);
        }
        Aw[r1 & 7] = a1;
        if (r1 >= 42)                                  // owned cD1 rows [32k,32k+32)
            nt_store(outb + ((size_t)(t1b + r1) * NB + 4) * F_DIM, d1);
        if (r1 < 73) {                                 // advance window: locals 2r1+8, 2r1+9
            xw[(2 * r1 + 8) & 7] = inb[(size_t)(2 * (t1b + r1) + 2) * F_DIM];
            xw[(2 * r1 + 9) & 7] = inb[(size_t)(2 * (t1b + r1) + 3) * F_DIM];
        }

        if ((r1 & 1) && r1 >= 7) {                     // level 2: r2 ready at r1 = 2r2+7
            const int r2 = (r1 - 7) >> 1;              // 0..33
            float a2 = 0.f, d2 = 0.f;
            #pragma unroll
            for (int j = 0; j < 8; ++j) {
                const float v = Aw[(2 * r2 + j) & 7];  // rows [r1-7, r1] = window, exact
                a2 = fmaf(v, RLO[j], a2);
                d2 = fmaf(v, RHI[j], d2);
            }
            Bw[r2 & 7] = a2;
            if (r2 >= 18)                              // owned cD2 rows [16k,16k+16)
                nt_store(outb + ((size_t)(t2b + r2) * NB + 3) * F_DIM, d2);

            if ((r2 & 1) && r2 >= 7) {                 // level 3: r3 ready at r2 = 2r3+7
                const int r3 = (r2 - 7) >> 1;          // 0..13
                float a3 = 0.f, d3 = 0.f;
                #pragma unroll
                for (int j = 0; j < 8; ++j) {
                    const float v = Bw[(2 * r3 + j) & 7];
                    a3 = fmaf(v, RLO[j], a3);
                    d3 = fmaf(v, RHI[j], d3);
                }
                Cw[r3 & 7] = a3;
                if (r3 >= 6)                           // owned cD3 rows [8k,8k+8)
                    nt_store(outb + ((size_t)(t3b + r3) * NB + 2) * F_DIM, d3);

                if ((r3 & 1) && r3 >= 7) {             // level 4: r4 ready at r3 = 2r4+7
                    const int r4 = (r3 - 7) >> 1;      // 0..3
                    float a4 = 0.f, d4 = 0.f;
                    #pragma unroll
                    for (int j = 0; j < 8; ++j) {
                        const float v = Cw[(2 * r4 + j) & 7];
                        a4 = fmaf(v, RLO[j], a4);
                        d4 = fmaf(v, RHI[j], d4);
                    }
                    const int t4 = 4 * k + r4;         // < 262 for k <= 63
                    nt_store(outb + ((size_t)t4 * NB + 1) * F_DIM, d4);
                    nt_store(outb + ((size_t)t4 * NB + 0) * F_DIM, a4);
                }
            }
        }
    }
}

// ---- edge cascade (full arrays, constant-folded reflection) — verified R4 code ----
template<int KX>
__device__ __forceinline__ void cascade(const float* __restrict__ inb,
                                        float* __restrict__ outb)
{
    constexpr bool DP = (KX == 65);               // k=65 needs 2-row-deeper cA3 tile
    constexpr int N1 = DP ? 82 : 74, N2 = DP ? 38 : 34, N3 = DP ? 16 : 14;
    constexpr int OWN1 = DP ? 50 : 42, OWN2 = DP ? 22 : 18, OWN3 = DP ? 8 : 6;
    constexpr int R1LO = (KX == 0) ? 42 : (KX == 1) ? 10 : 0;
    constexpr int R1HI = (KX == 64) ? 45 : (KX == 65) ? 21 : N1;
    constexpr int R2LO = (KX == 0) ? 18 : (KX == 1) ? 2 : 0;
    constexpr int R2HI = (KX == 64) ? 23 : (KX == 65) ? 11 : N2;
    constexpr int R3LO = (KX == 0) ? 6 : 0;
    constexpr int R3HI = (KX == 64) ? 12 : (KX == 65) ? 6 : N3;
    constexpr int MHI  = (KX == 65) ? 2 : 4;

    constexpr int k   = KX;
    constexpr int t1b = 32 * k - (DP ? 50 : 42);
    constexpr int t2b = 16 * k - (DP ? 22 : 18);
    constexpr int t3b = 8 * k  - (DP ? 8  : 6);

    float A[N1], B[N2], C[N3];

    float xw[8];
    #pragma unroll
    for (int j = 0; j < 8; ++j) {
        const int g = refl(2 * (t1b + R1LO) - 6 + j, T_LEN);
        xw[j] = inb[(size_t)g * F_DIM];
    }
    #pragma unroll
    for (int r1 = R1LO; r1 < R1HI; ++r1) {
        float a = 0.f, d = 0.f;
        #pragma unroll
        for (int j = 0; j < 8; ++j) { a = fmaf(xw[j], RLO[j], a); d = fmaf(xw[j], RHI[j], d); }
        A[r1] = a;
        const int t1 = t1b + r1;
        if (r1 >= OWN1)
            nt_store(outb + ((size_t)t1 * NB + 4) * F_DIM, d);
        if (r1 + 1 < R1HI) {
            #pragma unroll
            for (int j = 0; j < 6; ++j) xw[j] = xw[j + 2];
            const int g6 = refl(2 * t1 + 2, T_LEN), g7 = refl(2 * t1 + 3, T_LEN);
            xw[6] = inb[(size_t)g6 * F_DIM];
            xw[7] = inb[(size_t)g7 * F_DIM];
        }
    }

    #pragma unroll
    for (int r2 = R2LO; r2 < R2HI; ++r2) {
        float a = 0.f, d = 0.f;
        #pragma unroll
        for (int j = 0; j < 8; ++j) {
            const float v = A[refl(2 * (t2b + r2) - 6 + j, L1) - t1b];
            a = fmaf(v, RLO[j], a); d = fmaf(v, RHI[j], d);
        }
        B[r2] = a;
        if (r2 >= OWN2)
            nt_store(outb + ((size_t)(t2b + r2) * NB + 3) * F_DIM, d);
    }

    #pragma unroll
    for (int r3 = R3LO; r3 < R3HI; ++r3) {
        float a = 0.f, d = 0.f;
        #pragma unroll
        for (int j = 0; j < 8; ++j) {
            const float v = B[refl(2 * (t3b + r3) - 6 + j, L2) - t2b];
            a = fmaf(v, RLO[j], a); d = fmaf(v, RHI[j], d);
        }
        C[r3] = a;
        if (r3 >= OWN3)
            nt_store(outb + ((size_t)(t3b + r3) * NB + 2) * F_DIM, d);
    }

    #pragma unroll
    for (int m = 0; m < MHI; ++m) {
        float a = 0.f, d = 0.f;
        #pragma unroll
        for (int j = 0; j < 8; ++j) {
            const float v = C[refl(2 * (4 * k + m) - 6 + j, L3) - t3b];
            a = fmaf(v, RLO[j], a); d = fmaf(v, RHI[j], d);
        }
        const int t4 = 4 * k + m;
        nt_store(outb + ((size_t)t4 * NB + 1) * F_DIM, d);
        nt_store(outb + ((size_t)t4 * NB + 0) * F_DIM, a);
    }
}

// ---- kernel 1: interior cascades + all zero-fill (low VGPR, high occupancy) ----
extern "C" __global__ __launch_bounds__(256, 6)
void dwt_interior(const float* __restrict__ in, float* __restrict__ out)
{
    const int tid = threadIdx.x;
    const int per = gridDim.x >> 3;                  // bijective XCD swizzle (1984 % 8 == 0)
    const int wg  = (int)(blockIdx.x & 7) * per + (int)(blockIdx.x >> 3);
    const int b   = wg / 124;                        // 124 slots per batch
    const int j   = wg % 124;

    float* outB = out + (size_t)b * T_LEN * NB * F_DIM;

    if (j < 62) {                                    // interior cascade, k = j+2 in [2,63]
        const int k = j + 2;
        const float* inb = in + (size_t)b * T_LEN * F_DIM + tid;
        cascade_interior(inb, outB + tid, k);
    } else {                                         // zero-fill block
        const int slot = j - 62;                     // [0,62)
        if (slot < 2) {                              // t in [262,518), 2KB prefix
            const int t0 = 262 + slot * 128;
            fill_zeros<2>(outB, t0, t0 + 128, tid);
        } else if (slot < 8) {                       // t in [518,1029), 3KB prefix
            const int i = slot - 2;
            const int t0 = 518 + i * 86;
            fill_zeros<3>(outB, t0, (t0 + 86 < L2) ? t0 + 86 : L2, tid);
        } else if (slot < 24) {                      // t in [1029,2051), 4KB prefix
            const int i = slot - 8;
            const int t0 = 1029 + i * 64;
            fill_zeros<4>(outB, t0, (t0 + 64 < L1) ? t0 + 64 : L1, tid);
        } else {                                     // t in [2051,4096), full 5KB rows
            const int i = slot - 24;
            const int t0 = 2051 + i * 54;
            fill_zeros<5>(outB, t0, (t0 + 54 < T_LEN) ? t0 + 54 : T_LEN, tid);
        }
    }
}

// ---- kernel 2: the 4 edge tiles per batch (own VGPR budget, 64 blocks) ----
extern "C" __global__ __launch_bounds__(256)
void dwt_edge(const float* __restrict__ in, float* __restrict__ out)
{
    const int f   = threadIdx.x;
    const int b   = (int)blockIdx.x >> 2;
    const int sel = (int)blockIdx.x & 3;

    const float* inb = in + (size_t)b * T_LEN * F_DIM + f;
    float* outb = out + (size_t)b * T_LEN * NB * F_DIM + f;

    switch (sel) {
        case 0: cascade<0 >(inb, outb); break;
        case 1: cascade<1 >(inb, outb); break;
        case 2: cascade<64>(inb, outb); break;
        case 3: cascade<65>(inb, outb); break;
    }
}

extern "C" void kernel_launch(void* const* d_in, const int* in_sizes, int n_in,
                              void* d_out, int out_size, void* d_ws, size_t ws_size,
                              hipStream_t stream)
{
    const float* traj = (const float*)d_in[0];
    float* out = (float*)d_out;
    hipLaunchKernelGGL(dwt_interior, dim3(16 * 124), dim3(F_DIM), 0, stream, traj, out);
    hipLaunchKernelGGL(dwt_edge,     dim3(16 * 4),   dim3(F_DIM), 0, stream, traj, out);
}

// Round 7
// 69.967 us; speedup vs baseline: 1.3150x; 1.3150x over previous
//
#include <hip/hip_runtime.h>

// Fully-fused 4-level db4 DWT (pywt wavedec, symmetric, level=4).
// Input  trajectory: [B=16, T=4096, F=256] f32, feature-fastest.
// Output: [B, T, 5, F] f32; bands [cA4, cD4, cD3, cD2, cD1], zero-padded to T.
//
// R7 = R5 structure (single kernel, 16 b x 128 slots, verified) with ONE change:
// the interior cascade's level 1 issues its input loads in 38-row CHUNK BATCHES
// into a static register buffer (X[38] -> 16 output rows per chunk), instead of
// a 2-load shift window consumed on the next iteration. ~38 loads in flight vs 2
// -> load latency amortized; register tier unchanged (~200 VGPR, same as R5).
// Edge tiles (k in {0,1,64,65}: constant-folded reflection) and prefix zero-fill
// blocks are verbatim R5 (absmax=0 twice).
//
// out[n] = sum_j x_sym[2n+j-6] * DEC[7-j]; refl: i<0 -> -1-i, i>=L -> 2L-1-i.
// Lengths: L1=2051, L2=1029, L3=518, L4=262.

namespace {
constexpr int T_LEN = 4096;
constexpr int F_DIM = 256;
constexpr int NB    = 5;
constexpr int L1 = 2051, L2 = 1029, L3 = 518, L4 = 262;
}

typedef float f32x4 __attribute__((ext_vector_type(4)));

__device__ __constant__ float RLO[8] = {
     0.23037781330885523f,   0.7148465705525415f,   0.6308807679295904f,
    -0.02798376941698385f,  -0.18703481171888114f,  0.030841381835986965f,
     0.032883011666982945f, -0.010597401784997278f };

__device__ __constant__ float RHI[8] = {
    -0.010597401784997278f, -0.032883011666982945f, 0.030841381835986965f,
     0.18703481171888114f,  -0.02798376941698385f, -0.6308807679295904f,
     0.7148465705525415f,   -0.23037781330885523f };

__device__ __host__ constexpr int refl(int i, int L) {
    return (i < 0) ? (-1 - i) : ((i >= L) ? (2 * L - 1 - i) : i);
}

__device__ __forceinline__ void nt_store(float* p, float v) {
    __builtin_nontemporal_store(v, p);
}

// ---- zero-fill: rows [t0,t1) each get a Z*1KB zero prefix (dwordx4) ----
template<int Z>
__device__ __forceinline__ void fill_zeros(float* __restrict__ outB,
                                           int t0, int t1, int tid)
{
    const f32x4 z4 = {0.f, 0.f, 0.f, 0.f};
    for (int t = t0; t < t1; ++t) {
        float* row = outB + (size_t)t * NB * F_DIM;
        #pragma unroll
        for (int c0 = 0; c0 < Z * F_DIM; c0 += 4 * F_DIM) {
            const int c = c0 + tid * 4;
            if (c < Z * F_DIM)
                __builtin_nontemporal_store(z4, (f32x4*)(row + c));
        }
    }
}

// ---- interior cascade, k in [2,63]: chunk-batched level-1 loads ----
__device__ __forceinline__ void cascade_interior(const float* __restrict__ inb,
                                                 float* __restrict__ outb, int k)
{
    const int t1b = 32 * k - 42;                  // >= 22 for k >= 2; no reflection
    const int t2b = 16 * k - 18;
    const int t3b = 8  * k - 6;

    float A[74], B[34], C[14];

    // ---- level 1 in chunks: load 38 rows (batch), compute 16 rows ----
    #pragma unroll
    for (int c = 0; c < 5; ++c) {
        const int r1a   = 16 * c;                  // chunk's first r1
        const int nrows = (c < 4) ? 16 : 10;       // 4*16 + 10 = 74
        const int nload = 2 * nrows + 6;           // 38 / 26
        const int ibase = 2 * t1b + 32 * c - 6;    // in [38, 4095-…]; always in-bounds

        float X[38];
        #pragma unroll
        for (int i = 0; i < 38; ++i)
            if (i < nload)
                X[i] = inb[(size_t)(ibase + i) * F_DIM];

        #pragma unroll
        for (int r = 0; r < 16; ++r) {
            if (r < nrows) {
                const int r1 = r1a + r;
                float a = 0.f, d = 0.f;
                #pragma unroll
                for (int j = 0; j < 8; ++j) {
                    const float v = X[2 * r + j];
                    a = fmaf(v, RLO[j], a);
                    d = fmaf(v, RHI[j], d);
                }
                A[r1] = a;
                if (r1 >= 42)                      // owned cD1 rows [32k, 32k+32)
                    nt_store(outb + ((size_t)(t1b + r1) * NB + 4) * F_DIM, d);
            }
        }
    }

    // ---- level 2: cA1 -> cA2 + owned cD2 ----
    #pragma unroll
    for (int r2 = 0; r2 < 34; ++r2) {
        float a = 0.f, d = 0.f;
        #pragma unroll
        for (int j = 0; j < 8; ++j) {
            const float v = A[2 * r2 + j];
            a = fmaf(v, RLO[j], a); d = fmaf(v, RHI[j], d);
        }
        B[r2] = a;
        if (r2 >= 18)
            nt_store(outb + ((size_t)(t2b + r2) * NB + 3) * F_DIM, d);
    }

    // ---- level 3 ----
    #pragma unroll
    for (int r3 = 0; r3 < 14; ++r3) {
        float a = 0.f, d = 0.f;
        #pragma unroll
        for (int j = 0; j < 8; ++j) {
            const float v = B[2 * r3 + j];
            a = fmaf(v, RLO[j], a); d = fmaf(v, RHI[j], d);
        }
        C[r3] = a;
        if (r3 >= 6)
            nt_store(outb + ((size_t)(t3b + r3) * NB + 2) * F_DIM, d);
    }

    // ---- level 4 ----
    #pragma unroll
    for (int m = 0; m < 4; ++m) {
        float a = 0.f, d = 0.f;
        #pragma unroll
        for (int j = 0; j < 8; ++j) {
            const float v = C[2 * m + j];
            a = fmaf(v, RLO[j], a); d = fmaf(v, RHI[j], d);
        }
        const int t4 = 4 * k + m;                  // < 262 for k <= 63
        nt_store(outb + ((size_t)t4 * NB + 1) * F_DIM, d);
        nt_store(outb + ((size_t)t4 * NB + 0) * F_DIM, a);
    }
}

// ---- edge cascade (full arrays, constant-folded reflection) — verified R4/R5 ----
template<int KX>
__device__ __forceinline__ void cascade(const float* __restrict__ inb,
                                        float* __restrict__ outb)
{
    constexpr bool DP = (KX == 65);               // k=65 needs 2-row-deeper cA3 tile
    constexpr int N1 = DP ? 82 : 74, N2 = DP ? 38 : 34, N3 = DP ? 16 : 14;
    constexpr int OWN1 = DP ? 50 : 42, OWN2 = DP ? 22 : 18, OWN3 = DP ? 8 : 6;
    constexpr int R1LO = (KX == 0) ? 42 : (KX == 1) ? 10 : 0;
    constexpr int R1HI = (KX == 64) ? 45 : (KX == 65) ? 21 : N1;
    constexpr int R2LO = (KX == 0) ? 18 : (KX == 1) ? 2 : 0;
    constexpr int R2HI = (KX == 64) ? 23 : (KX == 65) ? 11 : N2;
    constexpr int R3LO = (KX == 0) ? 6 : 0;
    constexpr int R3HI = (KX == 64) ? 12 : (KX == 65) ? 6 : N3;
    constexpr int MHI  = (KX == 65) ? 2 : 4;

    constexpr int k   = KX;
    constexpr int t1b = 32 * k - (DP ? 50 : 42);
    constexpr int t2b = 16 * k - (DP ? 22 : 18);
    constexpr int t3b = 8 * k  - (DP ? 8  : 6);

    float A[N1], B[N2], C[N3];

    float xw[8];
    #pragma unroll
    for (int j = 0; j < 8; ++j) {
        const int g = refl(2 * (t1b + R1LO) - 6 + j, T_LEN);
        xw[j] = inb[(size_t)g * F_DIM];
    }
    #pragma unroll
    for (int r1 = R1LO; r1 < R1HI; ++r1) {
        float a = 0.f, d = 0.f;
        #pragma unroll
        for (int j = 0; j < 8; ++j) { a = fmaf(xw[j], RLO[j], a); d = fmaf(xw[j], RHI[j], d); }
        A[r1] = a;
        const int t1 = t1b + r1;
        if (r1 >= OWN1)
            nt_store(outb + ((size_t)t1 * NB + 4) * F_DIM, d);
        if (r1 + 1 < R1HI) {
            #pragma unroll
            for (int j = 0; j < 6; ++j) xw[j] = xw[j + 2];
            const int g6 = refl(2 * t1 + 2, T_LEN), g7 = refl(2 * t1 + 3, T_LEN);
            xw[6] = inb[(size_t)g6 * F_DIM];
            xw[7] = inb[(size_t)g7 * F_DIM];
        }
    }

    #pragma unroll
    for (int r2 = R2LO; r2 < R2HI; ++r2) {
        float a = 0.f, d = 0.f;
        #pragma unroll
        for (int j = 0; j < 8; ++j) {
            const float v = A[refl(2 * (t2b + r2) - 6 + j, L1) - t1b];
            a = fmaf(v, RLO[j], a); d = fmaf(v, RHI[j], d);
        }
        B[r2] = a;
        if (r2 >= OWN2)
            nt_store(outb + ((size_t)(t2b + r2) * NB + 3) * F_DIM, d);
    }

    #pragma unroll
    for (int r3 = R3LO; r3 < R3HI; ++r3) {
        float a = 0.f, d = 0.f;
        #pragma unroll
        for (int j = 0; j < 8; ++j) {
            const float v = B[refl(2 * (t3b + r3) - 6 + j, L2) - t2b];
            a = fmaf(v, RLO[j], a); d = fmaf(v, RHI[j], d);
        }
        C[r3] = a;
        if (r3 >= OWN3)
            nt_store(outb + ((size_t)(t3b + r3) * NB + 2) * F_DIM, d);
    }

    #pragma unroll
    for (int m = 0; m < MHI; ++m) {
        float a = 0.f, d = 0.f;
        #pragma unroll
        for (int j = 0; j < 8; ++j) {
            const float v = C[refl(2 * (4 * k + m) - 6 + j, L3) - t3b];
            a = fmaf(v, RLO[j], a); d = fmaf(v, RHI[j], d);
        }
        const int t4 = 4 * k + m;
        nt_store(outb + ((size_t)t4 * NB + 1) * F_DIM, d);
        nt_store(outb + ((size_t)t4 * NB + 0) * F_DIM, a);
    }
}

extern "C" __global__ __launch_bounds__(256)
void dwt_fused(const float* __restrict__ in, float* __restrict__ out)
{
    const int tid = threadIdx.x;
    const int per = gridDim.x >> 3;                      // bijective XCD swizzle (2048 % 8 == 0)
    const int wg  = (int)(blockIdx.x & 7) * per + (int)(blockIdx.x >> 3);
    const int b   = wg >> 7;                             // 128 slots per batch
    const int j   = wg & 127;

    float* outB = out + (size_t)b * T_LEN * NB * F_DIM;

    if (j < 66) {                                        // live cascade tile
        const float* inb = in + (size_t)b * T_LEN * F_DIM + tid;
        float* outb = outB + tid;
        switch (j) {
            case 0:  cascade<0 >(inb, outb); break;
            case 1:  cascade<1 >(inb, outb); break;
            case 64: cascade<64>(inb, outb); break;
            case 65: cascade<65>(inb, outb); break;
            default: cascade_interior(inb, outb, j); break;  // k in [2,63]
        }
    } else {                                             // zero-fill block
        const int slot = j - 66;                         // [0,62)
        if (slot < 2) {                                  // t in [262,518), 2KB prefix
            const int t0 = 262 + slot * 128;
            fill_zeros<2>(outB, t0, t0 + 128, tid);
        } else if (slot < 8) {                           // t in [518,1029), 3KB prefix
            const int i = slot - 2;
            const int t0 = 518 + i * 86;
            fill_zeros<3>(outB, t0, (t0 + 86 < L2) ? t0 + 86 : L2, tid);
        } else if (slot < 24) {                          // t in [1029,2051), 4KB prefix
            const int i = slot - 8;
            const int t0 = 1029 + i * 64;
            fill_zeros<4>(outB, t0, (t0 + 64 < L1) ? t0 + 64 : L1, tid);
        } else {                                         // t in [2051,4096), full 5KB rows
            const int i = slot - 24;
            const int t0 = 2051 + i * 54;
            fill_zeros<5>(outB, t0, (t0 + 54 < T_LEN) ? t0 + 54 : T_LEN, tid);
        }
    }
}

extern "C" void kernel_launch(void* const* d_in, const int* in_sizes, int n_in,
                              void* d_out, int out_size, void* d_ws, size_t ws_size,
                              hipStream_t stream)
{
    const float* traj = (const float*)d_in[0];
    float* out = (float*)d_out;
    hipLaunchKernelGGL(dwt_fused, dim3(16 * 128), dim3(F_DIM), 0, stream, traj, out);
}